// Round 3
// baseline (385.315 us; speedup 1.0000x reference)
//
#include <hip/hip_runtime.h>

#define NN 200000
#define NE 6400000
#define NB 800            // buckets: dst>>8, 256 nodes each
#define NWA 256           // scatter chunks (1 fat WG per CU)
#define CHUNK 25000       // NE / NWA exactly; single tile per WG
#define BUFCAP 44         // staged records per bucket (λ=31.25, σ=5.6 → +2.4σ; ovf parks rest)
#define CAPB 8704         // fixed per-bucket region in E (mean 8000, σ=89 → 8σ)
#define OVF 256           // overflow pair slots per WG (expected use ≈ 14)

// ws layout (4-byte units)
#define OFF_E    0                        // NB*CAPB = 6,963,200
#define OFF_C    6963200                  // NB: bucket cursors -> totals
#define OFF_DINV 7364000                  // NN floats
#define OFF_XS   7564000                  // 4*NN floats (16B aligned)
#define OFF_HS2  8364000                  // 4*NN floats (16B aligned)
// end: 9,164,000 ints = 36.7 MB

// Pass A: single-tile scatter (R12-proven form: ~31-record streams minimize
// random-line store transactions — the measured controlling variable).
// Records stay packed: src (18b) | dstLow (8b) << 18 — never rewritten.
__global__ void __launch_bounds__(1024) k_scatter(const int* __restrict__ src,
                                                  const int* __restrict__ dst,
                                                  int* __restrict__ C,
                                                  int* __restrict__ E) {
    __shared__ int wbase[NB];
    __shared__ int cnt[NB];
    __shared__ int buf[NB * BUFCAP];   // 140.8 KB staging (1 WG/CU)
    __shared__ int ovf[2 * OVF];
    __shared__ int ovfn;
    int w = blockIdx.x, t = threadIdx.x;
    for (int b = t; b < NB; b += 1024) cnt[b] = 0;
    if (t == 0) ovfn = 0;
    __syncthreads();
    int lo = w * CHUNK, hi = lo + CHUNK;
    for (int i = lo + t; i < hi; i += 1024) {
        int s = src[i], d = dst[i];
        int b = d >> 8;
        int rec = s | ((d & 255) << 18);
        int pos = atomicAdd(&cnt[b], 1);
        if (pos < BUFCAP) buf[b * BUFCAP + pos] = rec;
        else {
            int o = atomicAdd(&ovfn, 1);
            ovf[2 * o] = rec;
            ovf[2 * o + 1] = (b << 16) | pos;
        }
    }
    __syncthreads();
    for (int b = t; b < NB; b += 1024)
        wbase[b] = b * CAPB + atomicAdd(&C[b], cnt[b]);
    __syncthreads();
    for (int idx = t; idx < NB * BUFCAP; idx += 1024) {
        int b = idx / BUFCAP, j = idx - b * BUFCAP;
        int c = cnt[b];
        if (j < (c < BUFCAP ? c : BUFCAP)) E[wbase[b] + j] = buf[idx];
    }
    for (int o = t; o < ovfn; o += 1024) {
        int rec = ovf[2 * o], bp = ovf[2 * o + 1];
        E[wbase[bp >> 16] + (bp & 0xFFFF)] = rec;
    }
}

// Pass B (NEW): count-only per bucket — replaces the full counting sort.
// Reads the bucket's records once, LDS int-atomic degree count per dstLow,
// emits dinv + pre-scaled xs4. No stg array, no scan, no E rewrite.
__global__ void __launch_bounds__(512) k_count(const float* __restrict__ x,
                                               const int* __restrict__ E,
                                               const int* __restrict__ C,
                                               float* __restrict__ dinv,
                                               float4* __restrict__ xs4) {
    __shared__ int cnt[256];
    int b = blockIdx.x, t = threadIdx.x;
    if (t < 256) cnt[t] = 0;
    __syncthreads();
    int lo = b * CAPB, n = C[b];
    for (int i = t; i < n; i += 512)
        atomicAdd(&cnt[E[lo + i] >> 18], 1);
    __syncthreads();
    if (t < 256) {
        int node = (b << 8) + t;
        if (node < NN) {
            float di = rsqrtf(1.0f + (float)cnt[t]);
            dinv[node] = di;
            xs4[node] = make_float4(x[3 * node] * di, x[3 * node + 1] * di,
                                    x[3 * node + 2] * di, 0.f);
        }
    }
}

// Pass C (NEW): layer-1 bucket-accumulate gather. Streams the bucket's records,
// LDS float-atomic accumulate into acc[dstLow][3], then the dense
// W1/b1/relu/W2 epilogue runs 256-thread-PARALLEL (was lane0-serial).
__global__ void __launch_bounds__(512) k_gather1b(const int* __restrict__ E,
                                                  const int* __restrict__ C,
                                                  const float* __restrict__ dinv,
                                                  const float4* __restrict__ xs4,
                                                  const float* __restrict__ W1,
                                                  const float* __restrict__ b1,
                                                  const float* __restrict__ W2,
                                                  float4* __restrict__ hs24) {
    __shared__ float acc[256 * 3];     // stride 3 (coprime 32) -> conflict-light
    __shared__ float sW1[48], sb1[16], sW2[48];
    int b = blockIdx.x, t = threadIdx.x;
    if (t < 48) sW1[t] = W1[t];
    else if (t < 64) sb1[t - 48] = b1[t - 48];
    else if (t < 112) sW2[t - 64] = W2[t - 64];
    for (int i = t; i < 768; i += 512) acc[i] = 0.f;
    __syncthreads();
    int lo = b * CAPB, n = C[b];
#pragma unroll 4
    for (int i = t; i < n; i += 512) {
        int rec = E[lo + i];
        float4 m = xs4[rec & 0x3FFFF];
        int dl = (rec >> 18) * 3;
        atomicAdd(&acc[dl + 0], m.x);
        atomicAdd(&acc[dl + 1], m.y);
        atomicAdd(&acc[dl + 2], m.z);
    }
    __syncthreads();
    if (t < 256) {
        int node = (b << 8) + t;
        if (node < NN) {
            float di = dinv[node];
            float4 self = xs4[node];
            float a0 = di * (acc[3 * t + 0] + self.x);
            float a1 = di * (acc[3 * t + 1] + self.y);
            float a2 = di * (acc[3 * t + 2] + self.z);
            float o0 = 0.f, o1 = 0.f, o2 = 0.f;
#pragma unroll
            for (int k = 0; k < 16; ++k) {
                float v = a0 * sW1[k] + a1 * sW1[16 + k] + a2 * sW1[32 + k] + sb1[k];
                v = v > 0.f ? v : 0.f;
                o0 += v * sW2[3 * k + 0];
                o1 += v * sW2[3 * k + 1];
                o2 += v * sW2[3 * k + 2];
            }
            hs24[node] = make_float4(o0 * di, o1 * di, o2 * di, 0.f);
        }
    }
}

// Pass D (NEW): layer-2 bucket-accumulate gather + bias, coalesced store.
__global__ void __launch_bounds__(512) k_gather2b(const int* __restrict__ E,
                                                  const int* __restrict__ C,
                                                  const float* __restrict__ dinv,
                                                  const float4* __restrict__ hs24,
                                                  const float* __restrict__ b2,
                                                  float* __restrict__ out) {
    __shared__ float acc[256 * 3];
    __shared__ float smo[256 * 3];
    int b = blockIdx.x, t = threadIdx.x;
    for (int i = t; i < 768; i += 512) acc[i] = 0.f;
    __syncthreads();
    int lo = b * CAPB, n = C[b];
#pragma unroll 4
    for (int i = t; i < n; i += 512) {
        int rec = E[lo + i];
        float4 m = hs24[rec & 0x3FFFF];
        int dl = (rec >> 18) * 3;
        atomicAdd(&acc[dl + 0], m.x);
        atomicAdd(&acc[dl + 1], m.y);
        atomicAdd(&acc[dl + 2], m.z);
    }
    __syncthreads();
    if (t < 256) {
        int node = (b << 8) + t;
        if (node < NN) {
            float di = dinv[node];
            float4 self = hs24[node];
            smo[3 * t + 0] = di * (acc[3 * t + 0] + self.x) + b2[0];
            smo[3 * t + 1] = di * (acc[3 * t + 1] + self.y) + b2[1];
            smo[3 * t + 2] = di * (acc[3 * t + 2] + self.z) + b2[2];
        }
    }
    __syncthreads();
    int base = (b << 8) * 3;
    for (int i = t; i < 768; i += 512)
        if (base + i < NN * 3) out[base + i] = smo[i];
}

extern "C" void kernel_launch(void* const* d_in, const int* in_sizes, int n_in,
                              void* d_out, int out_size, void* d_ws, size_t ws_size,
                              hipStream_t stream) {
    const float* x  = (const float*)d_in[0];
    const int* ei   = (const int*)d_in[1];
    const float* W1 = (const float*)d_in[2];
    const float* b1 = (const float*)d_in[3];
    const float* W2 = (const float*)d_in[4];
    const float* b2 = (const float*)d_in[5];
    const int* src = ei;
    const int* dst = ei + NE;
    float* ws = (float*)d_ws;
    int* wsi = (int*)d_ws;
    float* out = (float*)d_out;

    int* E      = wsi + OFF_E;
    int* C      = wsi + OFF_C;
    float* dinv = ws + OFF_DINV;
    float4* xs4 = (float4*)(ws + OFF_XS);
    float4* hs24 = (float4*)(ws + OFF_HS2);

    hipMemsetAsync(C, 0, NB * sizeof(int), stream);
    k_scatter<<<NWA, 1024, 0, stream>>>(src, dst, C, E);
    k_count<<<NB, 512, 0, stream>>>(x, E, C, dinv, xs4);
    k_gather1b<<<NB, 512, 0, stream>>>(E, C, dinv, xs4, W1, b1, W2, hs24);
    k_gather2b<<<NB, 512, 0, stream>>>(E, C, dinv, hs24, b2, out);
}

// Round 4
// 232.717 us; speedup vs baseline: 1.6557x; 1.6557x over previous
//
#include <hip/hip_runtime.h>

#define NN 200000
#define NE 6400000
#define NB 800            // buckets: dst>>8, 256 nodes each
#define NWA 256           // scatter chunks (1 fat WG per CU)
#define CHUNK 25000       // NE / NWA exactly; single tile per WG
#define BUFCAP 44         // staged records per bucket (λ=31.25, σ=5.6 → +2.4σ; ovf parks rest)
#define CAPB 8704         // fixed per-bucket region in E (mean 8000, σ=89 → 8σ)
#define OVF 256           // overflow pair slots per WG (expected use ≈ 14)

// ws layout (4-byte units)
#define OFF_E    0                        // NB*CAPB = 6,963,200
#define OFF_C    6963200                  // NB: bucket cursors -> totals
#define OFF_RP   6964000                  // NN: CSR row start (absolute into E)
#define OFF_DG   7164000                  // NN: degree
#define OFF_DINV 7364000                  // NN floats
#define OFF_XS   7564000                  // 4*NN floats (16B aligned)
#define OFF_HS2  8364000                  // 4*NN floats (16B aligned)
// end: 9,164,000 ints = 36.7 MB

// Pass A: single-tile scatter (R12-proven form: ~31-record streams minimize
// random-line store transactions — the measured controlling variable).
__global__ void __launch_bounds__(1024) k_scatter(const int* __restrict__ src,
                                                  const int* __restrict__ dst,
                                                  int* __restrict__ C,
                                                  int* __restrict__ E) {
    __shared__ int wbase[NB];
    __shared__ int cnt[NB];
    __shared__ int buf[NB * BUFCAP];   // 140.8 KB staging (1 WG/CU)
    __shared__ int ovf[2 * OVF];
    __shared__ int ovfn;
    int w = blockIdx.x, t = threadIdx.x;
    for (int b = t; b < NB; b += 1024) cnt[b] = 0;
    if (t == 0) ovfn = 0;
    __syncthreads();
    int lo = w * CHUNK, hi = lo + CHUNK;
    for (int i = lo + t; i < hi; i += 1024) {
        int s = src[i], d = dst[i];
        int b = d >> 8;
        int rec = s | ((d & 255) << 18);
        int pos = atomicAdd(&cnt[b], 1);
        if (pos < BUFCAP) buf[b * BUFCAP + pos] = rec;
        else {
            int o = atomicAdd(&ovfn, 1);
            ovf[2 * o] = rec;
            ovf[2 * o + 1] = (b << 16) | pos;
        }
    }
    __syncthreads();
    for (int b = t; b < NB; b += 1024)
        wbase[b] = b * CAPB + atomicAdd(&C[b], cnt[b]);
    __syncthreads();
    for (int idx = t; idx < NB * BUFCAP; idx += 1024) {
        int b = idx / BUFCAP, j = idx - b * BUFCAP;
        int c = cnt[b];
        if (j < (c < BUFCAP ? c : BUFCAP)) E[wbase[b] + j] = buf[idx];
    }
    for (int o = t; o < ovfn; o += 1024) {
        int rec = ovf[2 * o], bp = ovf[2 * o + 1];
        E[wbase[bp >> 16] + (bp & 0xFFFF)] = rec;
    }
}

// Pass B: per-bucket counting sort into CSR (R12-proven form: cursor atomics,
// ~37 KB LDS -> 4 WG/CU, single dispatch round). Emits RP, DG, dinv, xs.
__global__ void __launch_bounds__(512) k_sort(const float* __restrict__ x, int* __restrict__ E,
                       const int* __restrict__ C,
                       int* __restrict__ RP, int* __restrict__ DG,
                       float* __restrict__ dinv, float4* __restrict__ xs4) {
    __shared__ int stg[CAPB];          // 34.8 KB
    __shared__ int cnt[256];
    __shared__ int pos[256];
    int b = blockIdx.x, t = threadIdx.x;
    int lo = b * CAPB;
    int n = C[b];
    if (t < 256) cnt[t] = 0;
    __syncthreads();
    for (int i = t; i < n; i += 512) {
        int r = E[lo + i];
        stg[i] = r;
        atomicAdd(&cnt[r >> 18], 1);
    }
    __syncthreads();
    if (t < 256) pos[t] = cnt[t];
    __syncthreads();
    for (int off = 1; off < 256; off <<= 1) {
        int v = 0;
        if (t < 256 && t >= off) v = pos[t - off];
        __syncthreads();
        if (t < 256) pos[t] += v;
        __syncthreads();
    }
    if (t < 256) {
        int c = cnt[t];
        int excl = pos[t] - c;
        int node = (b << 8) + t;
        if (node < NN) {
            RP[node] = lo + excl;
            DG[node] = c;
            float di = rsqrtf(1.0f + (float)c);
            dinv[node] = di;
            xs4[node] = make_float4(x[3 * node] * di, x[3 * node + 1] * di,
                                    x[3 * node + 2] * di, 0.f);
        }
        cnt[t] = excl;   // becomes the scatter cursor
    }
    __syncthreads();
    for (int i = t; i < n; i += 512) {
        int rec = stg[i];
        int l = rec >> 18;
        int slot = atomicAdd(&cnt[l], 1);
        E[lo + slot] = rec & 0x3FFFF;   // CSR: src only
    }
}

// Pass C: layer-1 gather, 16 lanes per node. NEW: dense W1/b1/relu/W2 epilogue
// runs on ALL 16 lanes (lane k = hidden unit k) instead of lane0-serial;
// weights via per-lane L1 loads -> no LDS, no __syncthreads, waves independent.
__global__ void k_gather1(const int* __restrict__ E, const int* __restrict__ RP,
                          const int* __restrict__ DG, const float* __restrict__ dinv,
                          const float4* __restrict__ xs4, const float* __restrict__ W1,
                          const float* __restrict__ b1, const float* __restrict__ W2,
                          float4* __restrict__ hs24) {
    int t = threadIdx.x;
    int seg = t >> 4, lane = t & 15;
    int n = blockIdx.x * 16 + seg;        // grid*16 == NN exactly
    int rp = RP[n], dg = DG[n];
    float s0 = 0.f, s1 = 0.f, s2 = 0.f;
    for (int j = lane; j < dg; j += 16) {
        float4 m = xs4[E[rp + j]];
        s0 += m.x; s1 += m.y; s2 += m.z;
    }
#pragma unroll
    for (int msk = 1; msk < 16; msk <<= 1) {
        s0 += __shfl_xor(s0, msk, 16);
        s1 += __shfl_xor(s1, msk, 16);
        s2 += __shfl_xor(s2, msk, 16);
    }
    // all 16 lanes hold the segment sum after the butterfly
    float di = dinv[n];
    float4 self = xs4[n];
    float a0 = di * (s0 + self.x);
    float a1 = di * (s1 + self.y);
    float a2 = di * (s2 + self.z);
    int k = lane;
    float v = a0 * W1[k] + a1 * W1[16 + k] + a2 * W1[32 + k] + b1[k];
    v = v > 0.f ? v : 0.f;
    float o0 = v * W2[3 * k + 0];
    float o1 = v * W2[3 * k + 1];
    float o2 = v * W2[3 * k + 2];
#pragma unroll
    for (int msk = 1; msk < 16; msk <<= 1) {
        o0 += __shfl_xor(o0, msk, 16);
        o1 += __shfl_xor(o1, msk, 16);
        o2 += __shfl_xor(o2, msk, 16);
    }
    if (lane == 0)
        hs24[n] = make_float4(o0 * di, o1 * di, o2 * di, 0.f);
}

// Pass D: layer-2 gather, 16 lanes per node + bias. All-lane epilogue,
// no LDS, no barrier.
__global__ void k_gather2(const int* __restrict__ E, const int* __restrict__ RP,
                          const int* __restrict__ DG, const float* __restrict__ dinv,
                          const float4* __restrict__ hs24, const float* __restrict__ b2,
                          float* __restrict__ out) {
    int t = threadIdx.x;
    int seg = t >> 4, lane = t & 15;
    int n = blockIdx.x * 16 + seg;
    int rp = RP[n], dg = DG[n];
    float s0 = 0.f, s1 = 0.f, s2 = 0.f;
    for (int j = lane; j < dg; j += 16) {
        float4 m = hs24[E[rp + j]];
        s0 += m.x; s1 += m.y; s2 += m.z;
    }
#pragma unroll
    for (int msk = 1; msk < 16; msk <<= 1) {
        s0 += __shfl_xor(s0, msk, 16);
        s1 += __shfl_xor(s1, msk, 16);
        s2 += __shfl_xor(s2, msk, 16);
    }
    if (lane == 0) {
        float di = dinv[n];
        float4 self = hs24[n];
        out[3 * n + 0] = di * (s0 + self.x) + b2[0];
        out[3 * n + 1] = di * (s1 + self.y) + b2[1];
        out[3 * n + 2] = di * (s2 + self.z) + b2[2];
    }
}

extern "C" void kernel_launch(void* const* d_in, const int* in_sizes, int n_in,
                              void* d_out, int out_size, void* d_ws, size_t ws_size,
                              hipStream_t stream) {
    const float* x  = (const float*)d_in[0];
    const int* ei   = (const int*)d_in[1];
    const float* W1 = (const float*)d_in[2];
    const float* b1 = (const float*)d_in[3];
    const float* W2 = (const float*)d_in[4];
    const float* b2 = (const float*)d_in[5];
    const int* src = ei;
    const int* dst = ei + NE;
    float* ws = (float*)d_ws;
    int* wsi = (int*)d_ws;
    float* out = (float*)d_out;

    int* E      = wsi + OFF_E;
    int* C      = wsi + OFF_C;
    int* RP     = wsi + OFF_RP;
    int* DG     = wsi + OFF_DG;
    float* dinv = ws + OFF_DINV;
    float4* xs4 = (float4*)(ws + OFF_XS);
    float4* hs24 = (float4*)(ws + OFF_HS2);

    hipMemsetAsync(C, 0, NB * sizeof(int), stream);
    k_scatter<<<NWA, 1024, 0, stream>>>(src, dst, C, E);
    k_sort<<<NB, 512, 0, stream>>>(x, E, C, RP, DG, dinv, xs4);
    k_gather1<<<NN / 16, 256, 0, stream>>>(E, RP, DG, dinv, xs4, W1, b1, W2, hs24);
    k_gather2<<<NN / 16, 256, 0, stream>>>(E, RP, DG, dinv, hs24, b2, out);
}

// Round 5
// 221.890 us; speedup vs baseline: 1.7365x; 1.0488x over previous
//
#include <hip/hip_runtime.h>

#define NN 200000
#define NE 6400000
#define NB 800            // buckets: dst>>8, 256 nodes each
#define NWA 256           // scatter chunks (1 fat WG per CU)
#define CHUNK 25000       // NE / NWA exactly; single tile per WG
#define CHUNK4 6250       // CHUNK/4 int4 records
#define BUFCAP 44         // staged records per bucket (λ=31.25, σ=5.6 → +2.4σ; ovf parks rest)
#define CAPB 8704         // fixed per-bucket region in E (mean 8000, σ=89 → 8σ)
#define OVF 256           // overflow pair slots per WG (expected use ≈ 14)

// ws layout (4-byte units)
#define OFF_E    0                        // NB*CAPB = 6,963,200
#define OFF_C    6963200                  // NB: bucket cursors -> totals
#define OFF_RP   6964000                  // NN: CSR row start (absolute into E)
#define OFF_DG   7164000                  // NN: degree
#define OFF_DINV 7364000                  // NN floats
#define OFF_XS   7564000                  // 4*NN floats (16B aligned)
#define OFF_HS2  8364000                  // 4*NN floats (16B aligned)
// end: 9,164,000 ints = 36.7 MB

// Pass A: single-tile scatter. NEW: int4-vectorized edge loads (4 edges per
// iter -> 7 iters instead of 25; quarters the latency exposures per wave).
__global__ void __launch_bounds__(1024) k_scatter(const int* __restrict__ src,
                                                  const int* __restrict__ dst,
                                                  int* __restrict__ C,
                                                  int* __restrict__ E) {
    __shared__ int wbase[NB];
    __shared__ int cnt[NB];
    __shared__ int buf[NB * BUFCAP];   // 140.8 KB staging (1 WG/CU)
    __shared__ int ovf[2 * OVF];
    __shared__ int ovfn;
    int w = blockIdx.x, t = threadIdx.x;
    for (int b = t; b < NB; b += 1024) cnt[b] = 0;
    if (t == 0) ovfn = 0;
    __syncthreads();
    int lo = w * CHUNK;
    const int4* src4 = (const int4*)(src + lo);
    const int4* dst4 = (const int4*)(dst + lo);
    for (int i = t; i < CHUNK4; i += 1024) {
        int4 s4 = src4[i];
        int4 d4 = dst4[i];
#pragma unroll
        for (int q = 0; q < 4; ++q) {
            int s = (&s4.x)[q], d = (&d4.x)[q];
            int b = d >> 8;
            int rec = s | ((d & 255) << 18);
            int pos = atomicAdd(&cnt[b], 1);
            if (pos < BUFCAP) buf[b * BUFCAP + pos] = rec;
            else {
                int o = atomicAdd(&ovfn, 1);
                ovf[2 * o] = rec;
                ovf[2 * o + 1] = (b << 16) | pos;
            }
        }
    }
    __syncthreads();
    for (int b = t; b < NB; b += 1024)
        wbase[b] = b * CAPB + atomicAdd(&C[b], cnt[b]);
    __syncthreads();
    for (int idx = t; idx < NB * BUFCAP; idx += 1024) {
        int b = idx / BUFCAP, j = idx - b * BUFCAP;
        int c = cnt[b];
        if (j < (c < BUFCAP ? c : BUFCAP)) E[wbase[b] + j] = buf[idx];
    }
    for (int o = t; o < ovfn; o += 1024) {
        int rec = ovf[2 * o], bp = ovf[2 * o + 1];
        E[wbase[bp >> 16] + (bp & 0xFFFF)] = rec;
    }
}

// Pass B: per-bucket counting sort into CSR. NEW: int4-vectorized record I/O
// in both streaming phases (4 iters instead of 16 per phase).
__global__ void __launch_bounds__(512) k_sort(const float* __restrict__ x, int* __restrict__ E,
                       const int* __restrict__ C,
                       int* __restrict__ RP, int* __restrict__ DG,
                       float* __restrict__ dinv, float4* __restrict__ xs4) {
    __shared__ int stg[CAPB];          // 34.8 KB
    __shared__ int cnt[256];
    __shared__ int pos[256];
    int b = blockIdx.x, t = threadIdx.x;
    int lo = b * CAPB;
    int n = C[b];
    int n4 = n >> 2;
    if (t < 256) cnt[t] = 0;
    __syncthreads();
    const int4* E4 = (const int4*)(E + lo);
    for (int i = t; i < n4; i += 512) {
        int4 r = E4[i];
        ((int4*)stg)[i] = r;
        atomicAdd(&cnt[((unsigned)r.x) >> 18], 1);
        atomicAdd(&cnt[((unsigned)r.y) >> 18], 1);
        atomicAdd(&cnt[((unsigned)r.z) >> 18], 1);
        atomicAdd(&cnt[((unsigned)r.w) >> 18], 1);
    }
    for (int i = (n4 << 2) + t; i < n; i += 512) {
        int r = E[lo + i];
        stg[i] = r;
        atomicAdd(&cnt[((unsigned)r) >> 18], 1);
    }
    __syncthreads();
    if (t < 256) pos[t] = cnt[t];
    __syncthreads();
    for (int off = 1; off < 256; off <<= 1) {
        int v = 0;
        if (t < 256 && t >= off) v = pos[t - off];
        __syncthreads();
        if (t < 256) pos[t] += v;
        __syncthreads();
    }
    if (t < 256) {
        int c = cnt[t];
        int excl = pos[t] - c;
        int node = (b << 8) + t;
        if (node < NN) {
            RP[node] = lo + excl;
            DG[node] = c;
            float di = rsqrtf(1.0f + (float)c);
            dinv[node] = di;
            xs4[node] = make_float4(x[3 * node] * di, x[3 * node + 1] * di,
                                    x[3 * node + 2] * di, 0.f);
        }
        cnt[t] = excl;   // becomes the scatter cursor
    }
    __syncthreads();
    for (int i = t; i < n4; i += 512) {
        int4 r = ((const int4*)stg)[i];
#pragma unroll
        for (int q = 0; q < 4; ++q) {
            int rec = (&r.x)[q];
            int slot = atomicAdd(&cnt[((unsigned)rec) >> 18], 1);
            E[lo + slot] = rec & 0x3FFFF;   // CSR: src only
        }
    }
    for (int i = (n4 << 2) + t; i < n; i += 512) {
        int rec = stg[i];
        int slot = atomicAdd(&cnt[((unsigned)rec) >> 18], 1);
        E[lo + slot] = rec & 0x3FFFF;
    }
}

// Pass C: layer-1 gather, 16 lanes per node; all-lane dense epilogue
// (R4-proven form: lane k = hidden unit k, weights via L1, no LDS/barrier).
__global__ void k_gather1(const int* __restrict__ E, const int* __restrict__ RP,
                          const int* __restrict__ DG, const float* __restrict__ dinv,
                          const float4* __restrict__ xs4, const float* __restrict__ W1,
                          const float* __restrict__ b1, const float* __restrict__ W2,
                          float4* __restrict__ hs24) {
    int t = threadIdx.x;
    int seg = t >> 4, lane = t & 15;
    int n = blockIdx.x * 16 + seg;        // grid*16 == NN exactly
    int rp = RP[n], dg = DG[n];
    float s0 = 0.f, s1 = 0.f, s2 = 0.f;
    for (int j = lane; j < dg; j += 16) {
        float4 m = xs4[E[rp + j]];
        s0 += m.x; s1 += m.y; s2 += m.z;
    }
#pragma unroll
    for (int msk = 1; msk < 16; msk <<= 1) {
        s0 += __shfl_xor(s0, msk, 16);
        s1 += __shfl_xor(s1, msk, 16);
        s2 += __shfl_xor(s2, msk, 16);
    }
    float di = dinv[n];
    float4 self = xs4[n];
    float a0 = di * (s0 + self.x);
    float a1 = di * (s1 + self.y);
    float a2 = di * (s2 + self.z);
    int k = lane;
    float v = a0 * W1[k] + a1 * W1[16 + k] + a2 * W1[32 + k] + b1[k];
    v = v > 0.f ? v : 0.f;
    float o0 = v * W2[3 * k + 0];
    float o1 = v * W2[3 * k + 1];
    float o2 = v * W2[3 * k + 2];
#pragma unroll
    for (int msk = 1; msk < 16; msk <<= 1) {
        o0 += __shfl_xor(o0, msk, 16);
        o1 += __shfl_xor(o1, msk, 16);
        o2 += __shfl_xor(o2, msk, 16);
    }
    if (lane == 0)
        hs24[n] = make_float4(o0 * di, o1 * di, o2 * di, 0.f);
}

// Pass D: layer-2 gather, 16 lanes per node + bias.
// Store via LDS write-combine (48 contiguous floats per block — R2 form).
__global__ void k_gather2(const int* __restrict__ E, const int* __restrict__ RP,
                          const int* __restrict__ DG, const float* __restrict__ dinv,
                          const float4* __restrict__ hs24, const float* __restrict__ b2,
                          float* __restrict__ out) {
    __shared__ float smo[48];
    int t = threadIdx.x;
    int seg = t >> 4, lane = t & 15;
    int n = blockIdx.x * 16 + seg;
    int rp = RP[n], dg = DG[n];
    float s0 = 0.f, s1 = 0.f, s2 = 0.f;
    for (int j = lane; j < dg; j += 16) {
        float4 m = hs24[E[rp + j]];
        s0 += m.x; s1 += m.y; s2 += m.z;
    }
#pragma unroll
    for (int msk = 1; msk < 16; msk <<= 1) {
        s0 += __shfl_xor(s0, msk, 16);
        s1 += __shfl_xor(s1, msk, 16);
        s2 += __shfl_xor(s2, msk, 16);
    }
    if (lane == 0) {
        float di = dinv[n];
        float4 self = hs24[n];
        smo[seg * 3 + 0] = di * (s0 + self.x) + b2[0];
        smo[seg * 3 + 1] = di * (s1 + self.y) + b2[1];
        smo[seg * 3 + 2] = di * (s2 + self.z) + b2[2];
    }
    __syncthreads();
    if (t < 48) out[(size_t)blockIdx.x * 48 + t] = smo[t];
}

extern "C" void kernel_launch(void* const* d_in, const int* in_sizes, int n_in,
                              void* d_out, int out_size, void* d_ws, size_t ws_size,
                              hipStream_t stream) {
    const float* x  = (const float*)d_in[0];
    const int* ei   = (const int*)d_in[1];
    const float* W1 = (const float*)d_in[2];
    const float* b1 = (const float*)d_in[3];
    const float* W2 = (const float*)d_in[4];
    const float* b2 = (const float*)d_in[5];
    const int* src = ei;
    const int* dst = ei + NE;
    float* ws = (float*)d_ws;
    int* wsi = (int*)d_ws;
    float* out = (float*)d_out;

    int* E      = wsi + OFF_E;
    int* C      = wsi + OFF_C;
    int* RP     = wsi + OFF_RP;
    int* DG     = wsi + OFF_DG;
    float* dinv = ws + OFF_DINV;
    float4* xs4 = (float4*)(ws + OFF_XS);
    float4* hs24 = (float4*)(ws + OFF_HS2);

    hipMemsetAsync(C, 0, NB * sizeof(int), stream);
    k_scatter<<<NWA, 1024, 0, stream>>>(src, dst, C, E);
    k_sort<<<NB, 512, 0, stream>>>(x, E, C, RP, DG, dinv, xs4);
    k_gather1<<<NN / 16, 256, 0, stream>>>(E, RP, DG, dinv, xs4, W1, b1, W2, hs24);
    k_gather2<<<NN / 16, 256, 0, stream>>>(E, RP, DG, dinv, hs24, b2, out);
}